// Round 6
// baseline (1307.200 us; speedup 1.0000x reference)
//
#include <hip/hip_runtime.h>
#include <hip/hip_cooperative_groups.h>
namespace cg = cooperative_groups;

#define DD 64
#define ROW 256        // output row stride in floats: D*(L+1)
#define CHUNK 1024     // scan chunk

// ---- fused CSR build (cooperative, single dispatch) -------------------------
// phases: zero counts + copy embed | count | chunk scan | partials scan |
//         add+cursor init | scatter.  Replaces 6 dispatches (round-4 chain
//         measured ~202us total; ideal memory+atomic work is ~40-60us -> the
//         rest was launch/drain gaps between short kernels).
__global__ __launch_bounds__(256) void k_csr_build(
        const float* __restrict__ ent, float* __restrict__ out,
        const int* __restrict__ heads, const int* __restrict__ rels,
        const int* __restrict__ tails, int* __restrict__ offs,
        int* __restrict__ running, int* __restrict__ packed,
        int* __restrict__ partials, int n, int nE, int nchunks) {
    cg::grid_group grid = cg::this_grid();
    __shared__ int lds[256];
    int t = threadIdx.x;
    long tid = (long)blockIdx.x * 256 + t;
    long gsz = (long)gridDim.x * 256;

    // ---- phase 0: zero counts (in 'running') + copy embed -> out slice 0 ----
    for (long i = tid; i < n; i += gsz) running[i] = 0;
    for (long idx = tid; idx < (long)n * 16; idx += gsz) {
        long r = idx >> 4; int q = (int)(idx & 15);
        ((float4*)(out + r * ROW))[q] = ((const float4*)(ent + r * DD))[q];
    }
    __threadfence();
    grid.sync();

    // ---- phase 1: count edges per head (device-scope atomics) ----
    for (long e = tid; e < nE; e += gsz)
        atomicAdd(running + heads[e], 1);
    __threadfence();
    grid.sync();

    // ---- phase 2: per-chunk exclusive scan + chunk totals ----
    for (int c = blockIdx.x; c < nchunks; c += gridDim.x) {
        int base = c * CHUNK;
        int cc[4]; int sum = 0;
        #pragma unroll
        for (int j = 0; j < 4; ++j) {
            int i = base + t * 4 + j;
            cc[j] = (i < n) ? running[i] : 0;    // counts live in 'running'
            sum += cc[j];
        }
        lds[t] = sum; __syncthreads();
        for (int d = 1; d < 256; d <<= 1) {
            int v = (t >= d) ? lds[t - d] : 0;
            __syncthreads();
            lds[t] += v;
            __syncthreads();
        }
        int excl = lds[t] - sum;
        if (t == 255) partials[c] = lds[255];
        int run = excl;
        #pragma unroll
        for (int j = 0; j < 4; ++j) {
            int i = base + t * 4 + j;
            if (i < n) offs[i] = run;
            run += cc[j];
        }
        __syncthreads();
    }
    __threadfence();
    grid.sync();

    // ---- phase 3: block 0 exclusive-scans the (<=128) chunk totals ----
    if (blockIdx.x == 0) {
        int v = (t < 128 && t < nchunks) ? partials[t] : 0;
        if (t < 128) lds[t] = v;
        __syncthreads();
        for (int d = 1; d < 128; d <<= 1) {
            int u = (t < 128 && t >= d) ? lds[t - d] : 0;
            __syncthreads();
            if (t < 128) lds[t] += u;
            __syncthreads();
        }
        if (t < 128) partials[t] = lds[t] - v;
    }
    __threadfence();
    grid.sync();

    // ---- phase 4: add chunk offsets, init scatter cursors, finalize ----
    for (long i = tid; i <= n; i += gsz) {
        if (i < n) {
            int v = offs[i] + partials[i >> 10];
            offs[i] = v;
            running[i] = v;      // scatter cursor init
        } else {
            offs[n] = nE;
        }
    }
    __threadfence();
    grid.sync();

    // ---- phase 5: scatter edges into CSR order; pack tail | (rel<<20) ----
    for (long e = tid; e < nE; e += gsz) {
        int h = heads[e];
        int pos = atomicAdd(running + h, 1);
        packed[pos] = tails[e] | (rels[e] << 20);
    }
}

// ---- fused KGAT layer -------------------------------------------------------
// wave per head; 4 edge-groups x 16 lanes, float4 per lane (4 dims).
// Edge descriptors batch-loaded (64/chunk) then distributed via shuffle.
// 2-deep software pipeline, 8 edges per iteration (4 gathers in flight).
// NOTE (rounds 1-5 evidence): natural allocation is 64 VGPR = the
// 8-waves/SIMD cliff. Do NOT add register pressure (68 VGPR -> +20us/layer),
// do NOT pin occupancy via __launch_bounds__ min-waves (32-VGPR alloc ->
// scratch spills -> +190us/layer), and do NOT shrink gather payload via
// fp16 shadow (cvt overhead > latency saved: +6us/layer). This exact
// version measured 92.1us/layer (rounds 0 & 4).
__global__ __launch_bounds__(256) void k_layer(
        const int* __restrict__ offs, const int* __restrict__ packed,
        const float* __restrict__ hbase, const float* __restrict__ relemb,
        const float* __restrict__ W, float* __restrict__ outbase,
        int n_heads, int nE) {
    __shared__ float Wt[DD * 65];      // padded transpose: Wt[k*65+j] = W[j][k]
    __shared__ float xs[4][DD];
    for (int idx = threadIdx.x; idx < DD * DD; idx += 256)
        Wt[(idx & 63) * 65 + (idx >> 6)] = W[idx];   // 2-way bank alias: free
    __syncthreads();

    int w = threadIdx.x >> 6, lane = threadIdx.x & 63;
    int g = lane >> 4, s = lane & 15;      // group 0..3, sublane 0..15

    for (int hd = blockIdx.x * 4 + w; hd < n_heads; hd += gridDim.x * 4) {
        const float4 eh4 = *(const float4*)(hbase + (long)hd * ROW + 4 * s);
        float4 acc = make_float4(0.f, 0.f, 0.f, 0.f);
        float ssum = 0.f;
        int p0 = offs[hd], pe = offs[hd + 1];

        for (int cbase = p0; cbase < pe; cbase += 64) {
            int clen = min(pe - cbase, 64);
            int vAll = packed[min(cbase + lane, nE - 1)];

            // prologue: stages 0 (edges g) and 1 (edges 4+g)
            int i0 = (g < clen) ? g : 0;
            int i1 = (4 + g < clen) ? 4 + g : 0;
            int v0 = __shfl(vAll, i0);
            int v1 = __shfl(vAll, i1);
            float4 tt0 = *(const float4*)(hbase + (long)(v0 & 0xFFFFF) * ROW + 4 * s);
            float4 rr0 = *(const float4*)(relemb + (v0 >> 20) * DD + 4 * s);
            float4 tt1 = *(const float4*)(hbase + (long)(v1 & 0xFFFFF) * ROW + 4 * s);
            float4 rr1 = *(const float4*)(relemb + (v1 >> 20) * DD + 4 * s);

            for (int i = 0; i < clen; i += 8) {
                // prefetch stages for i+8 (clamped; redundant tail hits cache)
                int ia = i + 8 + g;  ia = (ia < clen) ? ia : 0;
                int ib = i + 12 + g; ib = (ib < clen) ? ib : 0;
                int va = __shfl(vAll, ia);
                int vb = __shfl(vAll, ib);
                float4 tta = *(const float4*)(hbase + (long)(va & 0xFFFFF) * ROW + 4 * s);
                float4 rra = *(const float4*)(relemb + (va >> 20) * DD + 4 * s);
                float4 ttb = *(const float4*)(hbase + (long)(vb & 0xFFFFF) * ROW + 4 * s);
                float4 rrb = *(const float4*)(relemb + (vb >> 20) * DD + 4 * s);

                // ---- stage 0: edges i+g ----
                {
                    float sc = 0.f;
                    #pragma unroll
                    for (int q = 0; q < 4; ++q) {
                        float xq = (&eh4.x)[q] + (&rr0.x)[q];
                        float t = __expf(2.f * xq);
                        float th = 1.f - 2.f * __builtin_amdgcn_rcpf(t + 1.f);
                        sc += (&tt0.x)[q] * th;
                    }
                    #pragma unroll
                    for (int off = 1; off <= 8; off <<= 1) sc += __shfl_xor(sc, off);
                    float se = ((i + g) < clen) ? __expf(sc) : 0.f;
                    ssum += se;
                    acc.x += se * tt0.x; acc.y += se * tt0.y;
                    acc.z += se * tt0.z; acc.w += se * tt0.w;
                }
                // ---- stage 1: edges i+4+g ----
                {
                    float sc = 0.f;
                    #pragma unroll
                    for (int q = 0; q < 4; ++q) {
                        float xq = (&eh4.x)[q] + (&rr1.x)[q];
                        float t = __expf(2.f * xq);
                        float th = 1.f - 2.f * __builtin_amdgcn_rcpf(t + 1.f);
                        sc += (&tt1.x)[q] * th;
                    }
                    #pragma unroll
                    for (int off = 1; off <= 8; off <<= 1) sc += __shfl_xor(sc, off);
                    float se = ((i + 4 + g) < clen) ? __expf(sc) : 0.f;
                    ssum += se;
                    acc.x += se * tt1.x; acc.y += se * tt1.y;
                    acc.z += se * tt1.z; acc.w += se * tt1.w;
                }
                tt0 = tta; rr0 = rra; tt1 = ttb; rr1 = rrb;
            }
        }

        // combine the 4 groups' partial sums (lanes with equal s share dims)
        #pragma unroll
        for (int off = 16; off <= 32; off <<= 1) {
            acc.x += __shfl_xor(acc.x, off);
            acc.y += __shfl_xor(acc.y, off);
            acc.z += __shfl_xor(acc.z, off);
            acc.w += __shfl_xor(acc.w, off);
            ssum  += __shfl_xor(ssum,  off);
        }
        float inv = 1.f / (ssum + 1e-10f);
        float4 x4;
        x4.x = eh4.x + acc.x * inv;  x4.y = eh4.y + acc.y * inv;
        x4.z = eh4.z + acc.z * inv;  x4.w = eh4.w + acc.w * inv;
        if (g == 0) *(float4*)(&xs[w][4 * s]) = x4;   // wave-private slot

        // epilogue: y = leaky_relu(x @ W^T), one output dim per lane
        float y = 0.f;
        const float* xw = xs[w];
        #pragma unroll
        for (int k4 = 0; k4 < DD; k4 += 4) {
            float4 xv = *(const float4*)(xw + k4);
            y += xv.x * Wt[(k4 + 0) * 65 + lane];
            y += xv.y * Wt[(k4 + 1) * 65 + lane];
            y += xv.z * Wt[(k4 + 2) * 65 + lane];
            y += xv.w * Wt[(k4 + 3) * 65 + lane];
        }
        y = y >= 0.f ? y : 0.2f * y;
        outbase[(long)hd * ROW + lane] = y;
    }
}

extern "C" void kernel_launch(void* const* d_in, const int* in_sizes, int n_in,
                              void* d_out, int out_size, void* d_ws, size_t ws_size,
                              hipStream_t stream) {
    const float* ent   = (const float*)d_in[3];
    const float* rel   = (const float*)d_in[4];
    const float* Ws    = (const float*)d_in[5];
    const int* heads = (const int*)d_in[0];
    const int* rels  = (const int*)d_in[1];
    const int* tails = (const int*)d_in[2];
    float* out = (float*)d_out;

    const int nE = in_sizes[0];
    const int N  = in_sizes[3] / DD;
    const int L  = in_sizes[5] / (DD * DD);
    const int NREL = in_sizes[4] / (L * DD);

    int* offs    = (int*)d_ws;           // [N+1]
    int* running = offs + (N + 1);       // [N] (counts, then scatter cursor)
    int* packed  = running + N;          // [E]
    // partials in the TAIL of packed: consumed (phase 4) strictly before
    // phase 5 writes packed (grid.sync between). 128 slots >= nchunks.
    int* partials = packed + nE - 128;

    int nchunks = (N + CHUNK - 1) / CHUNK;   // 98 for N=100000

    // ---- CSR build: ONE cooperative dispatch (was 6) ----
    {
        void* args[] = { (void*)&ent, (void*)&out, (void*)&heads, (void*)&rels,
                         (void*)&tails, (void*)&offs, (void*)&running,
                         (void*)&packed, (void*)&partials,
                         (void*)&N, (void*)&nE, (void*)&nchunks };
        hipLaunchCooperativeKernel((const void*)k_csr_build,
                                   dim3(1024), dim3(256), args, 0, stream);
    }

    // ---- layers ----
    for (int l = 0; l < L; ++l) {
        k_layer<<<2048, dim3(256), 0, stream>>>(
            offs, packed, out + l * DD, rel + (long)l * NREL * DD,
            Ws + (long)l * DD * DD, out + (l + 1) * DD, N, nE);
    }
}

// Round 7
// 454.462 us; speedup vs baseline: 2.8764x; 2.8764x over previous
//
#include <hip/hip_runtime.h>

#define DD 64
#define ROW 256        // output row stride in floats: D*(L+1)
#define CHUNK 1024     // scan chunk

// ---- fused: copy entity_embed -> out slice 0, count edges per head,
//      and record each edge's within-head rank (atomicAdd return value).
//      The rank makes the scatter pass atomic-free. -------------------------
__global__ void k_copy_count(const float* __restrict__ ent, float* __restrict__ out,
                             const int* __restrict__ heads, int* __restrict__ counts,
                             int* __restrict__ permpos, int n_rows, int nE) {
    int idx = blockIdx.x * blockDim.x + threadIdx.x;
    int total = n_rows * 16;                       // n_rows*16 float4s
    if (idx < total) {
        int n = idx >> 4, q = idx & 15;
        const float4* src = (const float4*)(ent + (long)n * DD);
        float4* dst = (float4*)(out + (long)n * ROW);
        dst[q] = src[q];
    }
    if (idx < nE) {
        permpos[idx] = atomicAdd(counts + heads[idx], 1);
    }
}

// ---- scan step 1: per-chunk exclusive scan + chunk totals -------------------
__global__ __launch_bounds__(256) void k_scan_chunk(
        const int* __restrict__ counts, int* __restrict__ offs,
        int* __restrict__ partials, int n) {
    __shared__ int lds[256];
    int base = blockIdx.x * CHUNK;
    int t = threadIdx.x;
    int c[4]; int sum = 0;
    #pragma unroll
    for (int j = 0; j < 4; ++j) {
        int i = base + t * 4 + j;
        c[j] = (i < n) ? counts[i] : 0;
        sum += c[j];
    }
    lds[t] = sum; __syncthreads();
    for (int d = 1; d < 256; d <<= 1) {
        int v = (t >= d) ? lds[t - d] : 0;
        __syncthreads();
        lds[t] += v;
        __syncthreads();
    }
    int excl = lds[t] - sum;
    if (t == 255) partials[blockIdx.x] = lds[255];
    int run = excl;
    #pragma unroll
    for (int j = 0; j < 4; ++j) {
        int i = base + t * 4 + j;
        if (i < n) offs[i] = run;
        run += c[j];
    }
}

// ---- scan step 2+3 fused: every block locally scans the (<=128) chunk totals
// in LDS, then adds the chunk offset and finalizes offs. (No cursor init:
// scatter is atomic-free now.) ------------------------------------------------
__global__ __launch_bounds__(256) void k_scan_add(
        int* __restrict__ offs, const int* __restrict__ partials,
        int n, int nE, int nchunks) {
    __shared__ int lds[128];
    int t = threadIdx.x;
    if (t < 128) {
        int v = (t < nchunks) ? partials[t] : 0;
        lds[t] = v;
    }
    __syncthreads();
    // Hillis-Steele inclusive scan over 128 (2 waves participate)
    for (int d = 1; d < 128; d <<= 1) {
        int u = (t < 128 && t >= d) ? lds[t - d] : 0;
        __syncthreads();
        if (t < 128) lds[t] += u;
        __syncthreads();
    }
    int i = blockIdx.x * 256 + t;
    if (i < n) {
        int ck = i >> 10;
        int excl = (ck == 0) ? 0 : lds[ck - 1];
        offs[i] += excl;
    } else if (i == n) {
        offs[n] = nE;
    }
}

// ---- scatter edges into CSR order, ATOMIC-FREE: position = offs[h] +
//      within-head rank recorded during the count pass. Race-free bijection. --
__global__ void k_scatter(const int* __restrict__ heads, const int* __restrict__ rels,
                          const int* __restrict__ tails, const int* __restrict__ offs,
                          const int* __restrict__ permpos,
                          int* __restrict__ packed, int nE) {
    int e = blockIdx.x * 256 + threadIdx.x;
    if (e >= nE) return;
    int h = heads[e];
    packed[offs[h] + permpos[e]] = tails[e] | (rels[e] << 20);
}

// ---- fused KGAT layer -------------------------------------------------------
// wave per head; 4 edge-groups x 16 lanes, float4 per lane (4 dims).
// Edge descriptors batch-loaded (64/chunk) then distributed via shuffle.
// 2-deep software pipeline, 8 edges per iteration (4 gathers in flight).
// NOTE (rounds 1-6 evidence): natural allocation is 64 VGPR = the
// 8-waves/SIMD cliff. Do NOT add register pressure (68 VGPR -> +20us/layer),
// do NOT pin occupancy via __launch_bounds__ min-waves (32-VGPR alloc ->
// scratch spills -> +190us/layer), do NOT shrink gather payload via fp16
// shadow (cvt overhead > latency saved: +6us/layer), and do NOT use
// cooperative grid.sync anywhere (150us+/sync). This exact version measured
// 92.1us/layer (rounds 0 & 4).
__global__ __launch_bounds__(256) void k_layer(
        const int* __restrict__ offs, const int* __restrict__ packed,
        const float* __restrict__ hbase, const float* __restrict__ relemb,
        const float* __restrict__ W, float* __restrict__ outbase,
        int n_heads, int nE) {
    __shared__ float Wt[DD * 65];      // padded transpose: Wt[k*65+j] = W[j][k]
    __shared__ float xs[4][DD];
    for (int idx = threadIdx.x; idx < DD * DD; idx += 256)
        Wt[(idx & 63) * 65 + (idx >> 6)] = W[idx];   // 2-way bank alias: free
    __syncthreads();

    int w = threadIdx.x >> 6, lane = threadIdx.x & 63;
    int g = lane >> 4, s = lane & 15;      // group 0..3, sublane 0..15

    for (int hd = blockIdx.x * 4 + w; hd < n_heads; hd += gridDim.x * 4) {
        const float4 eh4 = *(const float4*)(hbase + (long)hd * ROW + 4 * s);
        float4 acc = make_float4(0.f, 0.f, 0.f, 0.f);
        float ssum = 0.f;
        int p0 = offs[hd], pe = offs[hd + 1];

        for (int cbase = p0; cbase < pe; cbase += 64) {
            int clen = min(pe - cbase, 64);
            int vAll = packed[min(cbase + lane, nE - 1)];

            // prologue: stages 0 (edges g) and 1 (edges 4+g)
            int i0 = (g < clen) ? g : 0;
            int i1 = (4 + g < clen) ? 4 + g : 0;
            int v0 = __shfl(vAll, i0);
            int v1 = __shfl(vAll, i1);
            float4 tt0 = *(const float4*)(hbase + (long)(v0 & 0xFFFFF) * ROW + 4 * s);
            float4 rr0 = *(const float4*)(relemb + (v0 >> 20) * DD + 4 * s);
            float4 tt1 = *(const float4*)(hbase + (long)(v1 & 0xFFFFF) * ROW + 4 * s);
            float4 rr1 = *(const float4*)(relemb + (v1 >> 20) * DD + 4 * s);

            for (int i = 0; i < clen; i += 8) {
                // prefetch stages for i+8 (clamped; redundant tail hits cache)
                int ia = i + 8 + g;  ia = (ia < clen) ? ia : 0;
                int ib = i + 12 + g; ib = (ib < clen) ? ib : 0;
                int va = __shfl(vAll, ia);
                int vb = __shfl(vAll, ib);
                float4 tta = *(const float4*)(hbase + (long)(va & 0xFFFFF) * ROW + 4 * s);
                float4 rra = *(const float4*)(relemb + (va >> 20) * DD + 4 * s);
                float4 ttb = *(const float4*)(hbase + (long)(vb & 0xFFFFF) * ROW + 4 * s);
                float4 rrb = *(const float4*)(relemb + (vb >> 20) * DD + 4 * s);

                // ---- stage 0: edges i+g ----
                {
                    float sc = 0.f;
                    #pragma unroll
                    for (int q = 0; q < 4; ++q) {
                        float xq = (&eh4.x)[q] + (&rr0.x)[q];
                        float t = __expf(2.f * xq);
                        float th = 1.f - 2.f * __builtin_amdgcn_rcpf(t + 1.f);
                        sc += (&tt0.x)[q] * th;
                    }
                    #pragma unroll
                    for (int off = 1; off <= 8; off <<= 1) sc += __shfl_xor(sc, off);
                    float se = ((i + g) < clen) ? __expf(sc) : 0.f;
                    ssum += se;
                    acc.x += se * tt0.x; acc.y += se * tt0.y;
                    acc.z += se * tt0.z; acc.w += se * tt0.w;
                }
                // ---- stage 1: edges i+4+g ----
                {
                    float sc = 0.f;
                    #pragma unroll
                    for (int q = 0; q < 4; ++q) {
                        float xq = (&eh4.x)[q] + (&rr1.x)[q];
                        float t = __expf(2.f * xq);
                        float th = 1.f - 2.f * __builtin_amdgcn_rcpf(t + 1.f);
                        sc += (&tt1.x)[q] * th;
                    }
                    #pragma unroll
                    for (int off = 1; off <= 8; off <<= 1) sc += __shfl_xor(sc, off);
                    float se = ((i + 4 + g) < clen) ? __expf(sc) : 0.f;
                    ssum += se;
                    acc.x += se * tt1.x; acc.y += se * tt1.y;
                    acc.z += se * tt1.z; acc.w += se * tt1.w;
                }
                tt0 = tta; rr0 = rra; tt1 = ttb; rr1 = rrb;
            }
        }

        // combine the 4 groups' partial sums (lanes with equal s share dims)
        #pragma unroll
        for (int off = 16; off <= 32; off <<= 1) {
            acc.x += __shfl_xor(acc.x, off);
            acc.y += __shfl_xor(acc.y, off);
            acc.z += __shfl_xor(acc.z, off);
            acc.w += __shfl_xor(acc.w, off);
            ssum  += __shfl_xor(ssum,  off);
        }
        float inv = 1.f / (ssum + 1e-10f);
        float4 x4;
        x4.x = eh4.x + acc.x * inv;  x4.y = eh4.y + acc.y * inv;
        x4.z = eh4.z + acc.z * inv;  x4.w = eh4.w + acc.w * inv;
        if (g == 0) *(float4*)(&xs[w][4 * s]) = x4;   // wave-private slot

        // epilogue: y = leaky_relu(x @ W^T), one output dim per lane
        float y = 0.f;
        const float* xw = xs[w];
        #pragma unroll
        for (int k4 = 0; k4 < DD; k4 += 4) {
            float4 xv = *(const float4*)(xw + k4);
            y += xv.x * Wt[(k4 + 0) * 65 + lane];
            y += xv.y * Wt[(k4 + 1) * 65 + lane];
            y += xv.z * Wt[(k4 + 2) * 65 + lane];
            y += xv.w * Wt[(k4 + 3) * 65 + lane];
        }
        y = y >= 0.f ? y : 0.2f * y;
        outbase[(long)hd * ROW + lane] = y;
    }
}

extern "C" void kernel_launch(void* const* d_in, const int* in_sizes, int n_in,
                              void* d_out, int out_size, void* d_ws, size_t ws_size,
                              hipStream_t stream) {
    const int*   heads = (const int*)d_in[0];
    const int*   rels  = (const int*)d_in[1];
    const int*   tails = (const int*)d_in[2];
    const float* ent   = (const float*)d_in[3];
    const float* rel   = (const float*)d_in[4];
    const float* Ws    = (const float*)d_in[5];
    float* out = (float*)d_out;

    const int nE = in_sizes[0];
    const int N  = in_sizes[3] / DD;
    const int L  = in_sizes[5] / (DD * DD);
    const int NREL = in_sizes[4] / (L * DD);

    int* offs    = (int*)d_ws;           // [N+1]
    int* counts  = offs + (N + 1);       // [N]
    int* packed  = counts + N;           // [E]
    int* permpos = packed + nE;          // [E]  within-head rank per edge
    // partials in the TAIL of packed: consumed by k_scan_add strictly
    // BEFORE k_scatter writes packed (stream order). 128 slots >= nchunks.
    int* partials = packed + nE - 128;

    dim3 blk(256);
    int nchunks = (N + CHUNK - 1) / CHUNK;   // 98 for N=100000
    int fuse_total = max(N * 16, nE);

    // ---- CSR build (atomic-free scatter; 5 dispatches) ----
    hipMemsetAsync(counts, 0, (size_t)N * sizeof(int), stream);
    k_copy_count<<<(fuse_total + 255) / 256, blk, 0, stream>>>(ent, out, heads, counts, permpos, N, nE);
    k_scan_chunk<<<nchunks, blk, 0, stream>>>(counts, offs, partials, N);
    k_scan_add<<<(N + 1 + 255) / 256, blk, 0, stream>>>(offs, partials, N, nE, nchunks);
    k_scatter<<<(nE + 255) / 256, blk, 0, stream>>>(heads, rels, tails, offs, permpos, packed, nE);

    // ---- layers ----
    for (int l = 0; l < L; ++l) {
        k_layer<<<2048, blk, 0, stream>>>(
            offs, packed, out + l * DD, rel + (long)l * NREL * DD,
            Ws + (long)l * DD * DD, out + (l + 1) * DD, N, nE);
    }
}

// Round 8
// 452.237 us; speedup vs baseline: 2.8905x; 1.0049x over previous
//
#include <hip/hip_runtime.h>

#define DD 64
#define ROW 256        // output row stride in floats: D*(L+1)
#define CAP 64         // fixed per-head slot capacity (Poisson(10) max ~30)

// ---- fused build: copy entity_embed -> out slice 0; count edges per head;
//      place each edge directly at packedF[h*CAP + rank] (rank = atomicAdd
//      return). No scan, no scatter pass. rank>=CAP sets *ovf (correctness
//      fallback; never taken for Poisson(10) data). permpos kept for the
//      fallback path only. ---------------------------------------------------
__global__ void k_build(const float* __restrict__ ent, float* __restrict__ out,
                        const int* __restrict__ heads, const int* __restrict__ rels,
                        const int* __restrict__ tails, int* __restrict__ counts,
                        int* __restrict__ ovf, int* __restrict__ permpos,
                        int* __restrict__ packedF, int n_rows, int nE) {
    int idx = blockIdx.x * blockDim.x + threadIdx.x;
    int total = n_rows * 16;                       // n_rows*16 float4s
    if (idx < total) {
        int n = idx >> 4, q = idx & 15;
        const float4* src = (const float4*)(ent + (long)n * DD);
        float4* dst = (float4*)(out + (long)n * ROW);
        dst[q] = src[q];
    }
    if (idx < nE) {
        int h = heads[idx];
        int rank = atomicAdd(counts + h, 1);
        permpos[idx] = rank;
        if (rank < CAP) packedF[(long)h * CAP + rank] = tails[idx] | (rels[idx] << 20);
        else *ovf = 1;
    }
}

// ---- fallback (only if some head overflowed CAP): single-block compact CSR
//      build. offs = exclusive scan of counts; packedF[offs[h]+permpos[e]]
//      rewritten compactly. Slow (~200us) but correct; guarded by *ovf. ------
__global__ __launch_bounds__(1024) void k_fallback(
        const int* __restrict__ heads, const int* __restrict__ rels,
        const int* __restrict__ tails, const int* __restrict__ counts,
        const int* __restrict__ ovf, int* __restrict__ offs,
        const int* __restrict__ permpos, int* __restrict__ packed,
        int n, int nE) {
    if (*ovf == 0) return;
    __shared__ int lds[1024];
    int t = threadIdx.x;
    int per = (n + 1023) / 1024;
    int lo = t * per, hi = min(lo + per, n);
    int sum = 0;
    for (int i = lo; i < hi; ++i) sum += counts[i];
    lds[t] = sum; __syncthreads();
    for (int d = 1; d < 1024; d <<= 1) {
        int u = (t >= d) ? lds[t - d] : 0;
        __syncthreads();
        lds[t] += u;
        __syncthreads();
    }
    int run = lds[t] - sum;
    for (int i = lo; i < hi; ++i) { offs[i] = run; run += counts[i]; }
    if (t == 0) offs[n] = nE;
    __syncthreads();
    for (int e = t; e < nE; e += 1024) {
        int h = heads[e];
        packed[offs[h] + permpos[e]] = tails[e] | (rels[e] << 20);
    }
}

// ---- fused KGAT layer -------------------------------------------------------
// wave per head; 4 edge-groups x 16 lanes, float4 per lane (4 dims).
// Edge descriptors batch-loaded (CAP/chunk) then distributed via shuffle.
// 2-deep software pipeline, 8 edges per iteration (4 gathers in flight).
// mode 0 (normal): head hd's edges live at [hd*CAP, hd*CAP+counts[hd]).
// mode 1 (overflow fallback): compact CSR via offs. Branch is wave-uniform.
// NOTE (rounds 1-6 evidence): natural allocation is 64 VGPR = the
// 8-waves/SIMD cliff. Do NOT add register pressure (68 VGPR -> +20us/layer),
// do NOT pin occupancy via __launch_bounds__ min-waves (32-VGPR alloc ->
// scratch spills -> +190us/layer), do NOT shrink gather payload via fp16
// shadow (+6us/layer), do NOT use cooperative grid.sync (150us+/sync).
// Hot loop byte-identical to the 92.1us/layer version (rounds 0/4/7).
__global__ __launch_bounds__(256) void k_layer(
        const int* __restrict__ offs, const int* __restrict__ counts,
        const int* __restrict__ ovf, const int* __restrict__ packed,
        const float* __restrict__ hbase, const float* __restrict__ relemb,
        const float* __restrict__ W, float* __restrict__ outbase,
        int n_heads, int nE) {
    __shared__ float Wt[DD * 65];      // padded transpose: Wt[k*65+j] = W[j][k]
    __shared__ float xs[4][DD];
    for (int idx = threadIdx.x; idx < DD * DD; idx += 256)
        Wt[(idx & 63) * 65 + (idx >> 6)] = W[idx];   // 2-way bank alias: free
    __syncthreads();

    const int mode = *ovf;
    const int cap = n_heads * CAP - 1;     // clamp bound inside packedF

    int w = threadIdx.x >> 6, lane = threadIdx.x & 63;
    int g = lane >> 4, s = lane & 15;      // group 0..3, sublane 0..15

    for (int hd = blockIdx.x * 4 + w; hd < n_heads; hd += gridDim.x * 4) {
        const float4 eh4 = *(const float4*)(hbase + (long)hd * ROW + 4 * s);
        float4 acc = make_float4(0.f, 0.f, 0.f, 0.f);
        float ssum = 0.f;
        int p0, pe;
        if (mode == 0) { p0 = hd << 6; pe = p0 + counts[hd]; }
        else           { p0 = offs[hd]; pe = offs[hd + 1]; }

        for (int cbase = p0; cbase < pe; cbase += 64) {
            int clen = min(pe - cbase, 64);
            int vAll = packed[min(cbase + lane, cap)];

            // prologue: stages 0 (edges g) and 1 (edges 4+g)
            int i0 = (g < clen) ? g : 0;
            int i1 = (4 + g < clen) ? 4 + g : 0;
            int v0 = __shfl(vAll, i0);
            int v1 = __shfl(vAll, i1);
            float4 tt0 = *(const float4*)(hbase + (long)(v0 & 0xFFFFF) * ROW + 4 * s);
            float4 rr0 = *(const float4*)(relemb + (v0 >> 20) * DD + 4 * s);
            float4 tt1 = *(const float4*)(hbase + (long)(v1 & 0xFFFFF) * ROW + 4 * s);
            float4 rr1 = *(const float4*)(relemb + (v1 >> 20) * DD + 4 * s);

            for (int i = 0; i < clen; i += 8) {
                // prefetch stages for i+8 (clamped; redundant tail hits cache)
                int ia = i + 8 + g;  ia = (ia < clen) ? ia : 0;
                int ib = i + 12 + g; ib = (ib < clen) ? ib : 0;
                int va = __shfl(vAll, ia);
                int vb = __shfl(vAll, ib);
                float4 tta = *(const float4*)(hbase + (long)(va & 0xFFFFF) * ROW + 4 * s);
                float4 rra = *(const float4*)(relemb + (va >> 20) * DD + 4 * s);
                float4 ttb = *(const float4*)(hbase + (long)(vb & 0xFFFFF) * ROW + 4 * s);
                float4 rrb = *(const float4*)(relemb + (vb >> 20) * DD + 4 * s);

                // ---- stage 0: edges i+g ----
                {
                    float sc = 0.f;
                    #pragma unroll
                    for (int q = 0; q < 4; ++q) {
                        float xq = (&eh4.x)[q] + (&rr0.x)[q];
                        float t = __expf(2.f * xq);
                        float th = 1.f - 2.f * __builtin_amdgcn_rcpf(t + 1.f);
                        sc += (&tt0.x)[q] * th;
                    }
                    #pragma unroll
                    for (int off = 1; off <= 8; off <<= 1) sc += __shfl_xor(sc, off);
                    float se = ((i + g) < clen) ? __expf(sc) : 0.f;
                    ssum += se;
                    acc.x += se * tt0.x; acc.y += se * tt0.y;
                    acc.z += se * tt0.z; acc.w += se * tt0.w;
                }
                // ---- stage 1: edges i+4+g ----
                {
                    float sc = 0.f;
                    #pragma unroll
                    for (int q = 0; q < 4; ++q) {
                        float xq = (&eh4.x)[q] + (&rr1.x)[q];
                        float t = __expf(2.f * xq);
                        float th = 1.f - 2.f * __builtin_amdgcn_rcpf(t + 1.f);
                        sc += (&tt1.x)[q] * th;
                    }
                    #pragma unroll
                    for (int off = 1; off <= 8; off <<= 1) sc += __shfl_xor(sc, off);
                    float se = ((i + 4 + g) < clen) ? __expf(sc) : 0.f;
                    ssum += se;
                    acc.x += se * tt1.x; acc.y += se * tt1.y;
                    acc.z += se * tt1.z; acc.w += se * tt1.w;
                }
                tt0 = tta; rr0 = rra; tt1 = ttb; rr1 = rrb;
            }
        }

        // combine the 4 groups' partial sums (lanes with equal s share dims)
        #pragma unroll
        for (int off = 16; off <= 32; off <<= 1) {
            acc.x += __shfl_xor(acc.x, off);
            acc.y += __shfl_xor(acc.y, off);
            acc.z += __shfl_xor(acc.z, off);
            acc.w += __shfl_xor(acc.w, off);
            ssum  += __shfl_xor(ssum,  off);
        }
        float inv = 1.f / (ssum + 1e-10f);
        float4 x4;
        x4.x = eh4.x + acc.x * inv;  x4.y = eh4.y + acc.y * inv;
        x4.z = eh4.z + acc.z * inv;  x4.w = eh4.w + acc.w * inv;
        if (g == 0) *(float4*)(&xs[w][4 * s]) = x4;   // wave-private slot

        // epilogue: y = leaky_relu(x @ W^T), one output dim per lane
        float y = 0.f;
        const float* xw = xs[w];
        #pragma unroll
        for (int k4 = 0; k4 < DD; k4 += 4) {
            float4 xv = *(const float4*)(xw + k4);
            y += xv.x * Wt[(k4 + 0) * 65 + lane];
            y += xv.y * Wt[(k4 + 1) * 65 + lane];
            y += xv.z * Wt[(k4 + 2) * 65 + lane];
            y += xv.w * Wt[(k4 + 3) * 65 + lane];
        }
        y = y >= 0.f ? y : 0.2f * y;
        outbase[(long)hd * ROW + lane] = y;
    }
}

extern "C" void kernel_launch(void* const* d_in, const int* in_sizes, int n_in,
                              void* d_out, int out_size, void* d_ws, size_t ws_size,
                              hipStream_t stream) {
    const int*   heads = (const int*)d_in[0];
    const int*   rels  = (const int*)d_in[1];
    const int*   tails = (const int*)d_in[2];
    const float* ent   = (const float*)d_in[3];
    const float* rel   = (const float*)d_in[4];
    const float* Ws    = (const float*)d_in[5];
    float* out = (float*)d_out;

    const int nE = in_sizes[0];
    const int N  = in_sizes[3] / DD;
    const int L  = in_sizes[5] / (DD * DD);
    const int NREL = in_sizes[4] / (L * DD);

    // workspace layout (ints): counts[N] | ovf[1] | offs[N+1] | permpos[E] |
    // packedF[N*CAP].  Total ~= 66N + E + 2 ints ~= 30.5 MB (ws >= 34.4 MB
    // proven in round 5).
    int* counts  = (int*)d_ws;            // [N]
    int* ovf     = counts + N;            // [1]
    int* offs    = ovf + 1;               // [N+1]  (fallback only)
    int* permpos = offs + (N + 1);        // [E]    (fallback only)
    int* packedF = permpos + nE;          // [N*CAP]

    dim3 blk(256);
    int fuse_total = max(N * 16, nE);

    // ---- CSR-free build: memset + one fused kernel + guarded fallback ----
    hipMemsetAsync(counts, 0, (size_t)(N + 1) * sizeof(int), stream);  // counts+ovf
    k_build<<<(fuse_total + 255) / 256, blk, 0, stream>>>(
        ent, out, heads, rels, tails, counts, ovf, permpos, packedF, N, nE);
    k_fallback<<<1, 1024, 0, stream>>>(
        heads, rels, tails, counts, ovf, offs, permpos, packedF, N, nE);

    // ---- layers ----
    for (int l = 0; l < L; ++l) {
        k_layer<<<2048, blk, 0, stream>>>(
            offs, counts, ovf, packedF, out + l * DD, rel + (long)l * NREL * DD,
            Ws + (long)l * DD * DD, out + (l + 1) * DD, N, nE);
    }
}

// Round 9
// 444.420 us; speedup vs baseline: 2.9414x; 1.0176x over previous
//
#include <hip/hip_runtime.h>

#define DD 64
#define ROW 256        // output row stride in floats: D*(L+1)
#define CAP 32         // fixed per-head slot capacity (Poisson(10) max ~28)
#define CAPSH 5

// ---- fused build: copy entity_embed -> out slice 0; count edges per head;
//      place each edge directly at packedF[h*CAP + rank] (rank = atomicAdd
//      return). No scan, no scatter pass. rank>=CAP sets *ovf (correctness
//      fallback; never taken for Poisson(10) data). permpos kept for the
//      fallback path only. ---------------------------------------------------
__global__ void k_build(const float* __restrict__ ent, float* __restrict__ out,
                        const int* __restrict__ heads, const int* __restrict__ rels,
                        const int* __restrict__ tails, int* __restrict__ counts,
                        int* __restrict__ ovf, int* __restrict__ permpos,
                        int* __restrict__ packedF, int n_rows, int nE) {
    int idx = blockIdx.x * blockDim.x + threadIdx.x;
    int total = n_rows * 16;                       // n_rows*16 float4s
    if (idx < total) {
        int n = idx >> 4, q = idx & 15;
        const float4* src = (const float4*)(ent + (long)n * DD);
        float4* dst = (float4*)(out + (long)n * ROW);
        dst[q] = src[q];
    }
    if (idx < nE) {
        int h = heads[idx];
        int rank = atomicAdd(counts + h, 1);
        permpos[idx] = rank;
        if (rank < CAP) packedF[((long)h << CAPSH) + rank] = tails[idx] | (rels[idx] << 20);
        else *ovf = 1;
    }
}

// ---- fallback (only if some head overflowed CAP): single-block compact CSR
//      build. offs = exclusive scan of counts; packedF[offs[h]+permpos[e]]
//      rewritten compactly. Slow (~200us) but correct; guarded by *ovf. ------
__global__ __launch_bounds__(1024) void k_fallback(
        const int* __restrict__ heads, const int* __restrict__ rels,
        const int* __restrict__ tails, const int* __restrict__ counts,
        const int* __restrict__ ovf, int* __restrict__ offs,
        const int* __restrict__ permpos, int* __restrict__ packed,
        int n, int nE) {
    if (*ovf == 0) return;
    __shared__ int lds[1024];
    int t = threadIdx.x;
    int per = (n + 1023) / 1024;
    int lo = t * per, hi = min(lo + per, n);
    int sum = 0;
    for (int i = lo; i < hi; ++i) sum += counts[i];
    lds[t] = sum; __syncthreads();
    for (int d = 1; d < 1024; d <<= 1) {
        int u = (t >= d) ? lds[t - d] : 0;
        __syncthreads();
        lds[t] += u;
        __syncthreads();
    }
    int run = lds[t] - sum;
    for (int i = lo; i < hi; ++i) { offs[i] = run; run += counts[i]; }
    if (t == 0) offs[n] = nE;
    __syncthreads();
    for (int e = t; e < nE; e += 1024) {
        int h = heads[e];
        packed[offs[h] + permpos[e]] = tails[e] | (rels[e] << 20);
    }
}

// ---- fused KGAT layer -------------------------------------------------------
// wave per head; 4 edge-groups x 16 lanes, float4 per lane (4 dims).
// 2-deep software pipeline, 8 edges per iteration (4 gathers in flight).
// mode 0 (normal): head hd's edges at [hd*CAP, hd*CAP+counts[hd]), CAP=32 ->
// descriptor footprint 12.8MB (per-XCD ~1.6MB: L2-resident). Descriptor load
// issued BEFORE counts/eh4 (p0 independent of counts in mode 0) -> breaks the
// round-8 serial chain counts->vAll that cost +14us/layer.
// mode 1 (overflow fallback): compact CSR via offs; chunk loop reloads.
// NOTE (rounds 1-8 evidence): natural allocation is 64 VGPR = the
// 8-waves/SIMD cliff. Do NOT add register pressure (68 VGPR -> +20us/layer),
// do NOT pin occupancy via __launch_bounds__ min-waves (32-VGPR alloc ->
// spills -> +190us/layer), no fp16 shadow (+6us/layer), no grid.sync
// (150us+/sync). Hot loop byte-identical to the 92.1us/layer version.
__global__ __launch_bounds__(256) void k_layer(
        const int* __restrict__ offs, const int* __restrict__ counts,
        const int* __restrict__ ovf, const int* __restrict__ packed,
        const float* __restrict__ hbase, const float* __restrict__ relemb,
        const float* __restrict__ W, float* __restrict__ outbase,
        int n_heads, int nE) {
    __shared__ float Wt[DD * 65];      // padded transpose: Wt[k*65+j] = W[j][k]
    __shared__ float xs[4][DD];
    const int mode = *ovf;
    for (int idx = threadIdx.x; idx < DD * DD; idx += 256)
        Wt[(idx & 63) * 65 + (idx >> 6)] = W[idx];   // 2-way bank alias: free
    __syncthreads();

    const int cap = (n_heads << CAPSH) - 1;   // clamp bound inside packedF

    int w = threadIdx.x >> 6, lane = threadIdx.x & 63;
    int g = lane >> 4, s = lane & 15;      // group 0..3, sublane 0..15

    for (int hd = blockIdx.x * 4 + w; hd < n_heads; hd += gridDim.x * 4) {
        // ---- issue descriptor load FIRST (mode 0: p0 needs no counts) ----
        int p0 = (mode == 0) ? (hd << CAPSH) : offs[hd];
        int vAll = packed[min(p0 + lane, cap)];
        int pe = (mode == 0) ? p0 + counts[hd] : offs[hd + 1];
        const float4 eh4 = *(const float4*)(hbase + (long)hd * ROW + 4 * s);
        float4 acc = make_float4(0.f, 0.f, 0.f, 0.f);
        float ssum = 0.f;

        for (int cbase = p0; cbase < pe; cbase += 64) {
            int clen = min(pe - cbase, 64);
            // vAll for this chunk already loaded (preloaded before loop /
            // at the bottom of the previous iteration)

            // prologue: stages 0 (edges g) and 1 (edges 4+g)
            int i0 = (g < clen) ? g : 0;
            int i1 = (4 + g < clen) ? 4 + g : 0;
            int v0 = __shfl(vAll, i0);
            int v1 = __shfl(vAll, i1);
            float4 tt0 = *(const float4*)(hbase + (long)(v0 & 0xFFFFF) * ROW + 4 * s);
            float4 rr0 = *(const float4*)(relemb + (v0 >> 20) * DD + 4 * s);
            float4 tt1 = *(const float4*)(hbase + (long)(v1 & 0xFFFFF) * ROW + 4 * s);
            float4 rr1 = *(const float4*)(relemb + (v1 >> 20) * DD + 4 * s);

            for (int i = 0; i < clen; i += 8) {
                // prefetch stages for i+8 (clamped; redundant tail hits cache)
                int ia = i + 8 + g;  ia = (ia < clen) ? ia : 0;
                int ib = i + 12 + g; ib = (ib < clen) ? ib : 0;
                int va = __shfl(vAll, ia);
                int vb = __shfl(vAll, ib);
                float4 tta = *(const float4*)(hbase + (long)(va & 0xFFFFF) * ROW + 4 * s);
                float4 rra = *(const float4*)(relemb + (va >> 20) * DD + 4 * s);
                float4 ttb = *(const float4*)(hbase + (long)(vb & 0xFFFFF) * ROW + 4 * s);
                float4 rrb = *(const float4*)(relemb + (vb >> 20) * DD + 4 * s);

                // ---- stage 0: edges i+g ----
                {
                    float sc = 0.f;
                    #pragma unroll
                    for (int q = 0; q < 4; ++q) {
                        float xq = (&eh4.x)[q] + (&rr0.x)[q];
                        float t = __expf(2.f * xq);
                        float th = 1.f - 2.f * __builtin_amdgcn_rcpf(t + 1.f);
                        sc += (&tt0.x)[q] * th;
                    }
                    #pragma unroll
                    for (int off = 1; off <= 8; off <<= 1) sc += __shfl_xor(sc, off);
                    float se = ((i + g) < clen) ? __expf(sc) : 0.f;
                    ssum += se;
                    acc.x += se * tt0.x; acc.y += se * tt0.y;
                    acc.z += se * tt0.z; acc.w += se * tt0.w;
                }
                // ---- stage 1: edges i+4+g ----
                {
                    float sc = 0.f;
                    #pragma unroll
                    for (int q = 0; q < 4; ++q) {
                        float xq = (&eh4.x)[q] + (&rr1.x)[q];
                        float t = __expf(2.f * xq);
                        float th = 1.f - 2.f * __builtin_amdgcn_rcpf(t + 1.f);
                        sc += (&tt1.x)[q] * th;
                    }
                    #pragma unroll
                    for (int off = 1; off <= 8; off <<= 1) sc += __shfl_xor(sc, off);
                    float se = ((i + 4 + g) < clen) ? __expf(sc) : 0.f;
                    ssum += se;
                    acc.x += se * tt1.x; acc.y += se * tt1.y;
                    acc.z += se * tt1.z; acc.w += se * tt1.w;
                }
                tt0 = tta; rr0 = rra; tt1 = ttb; rr1 = rrb;
            }

            // preload next chunk's descriptors (mode 1 only in practice)
            if (cbase + 64 < pe) vAll = packed[min(cbase + 64 + lane, cap)];
        }

        // combine the 4 groups' partial sums (lanes with equal s share dims)
        #pragma unroll
        for (int off = 16; off <= 32; off <<= 1) {
            acc.x += __shfl_xor(acc.x, off);
            acc.y += __shfl_xor(acc.y, off);
            acc.z += __shfl_xor(acc.z, off);
            acc.w += __shfl_xor(acc.w, off);
            ssum  += __shfl_xor(ssum,  off);
        }
        float inv = 1.f / (ssum + 1e-10f);
        float4 x4;
        x4.x = eh4.x + acc.x * inv;  x4.y = eh4.y + acc.y * inv;
        x4.z = eh4.z + acc.z * inv;  x4.w = eh4.w + acc.w * inv;
        if (g == 0) *(float4*)(&xs[w][4 * s]) = x4;   // wave-private slot

        // epilogue: y = leaky_relu(x @ W^T), one output dim per lane
        float y = 0.f;
        const float* xw = xs[w];
        #pragma unroll
        for (int k4 = 0; k4 < DD; k4 += 4) {
            float4 xv = *(const float4*)(xw + k4);
            y += xv.x * Wt[(k4 + 0) * 65 + lane];
            y += xv.y * Wt[(k4 + 1) * 65 + lane];
            y += xv.z * Wt[(k4 + 2) * 65 + lane];
            y += xv.w * Wt[(k4 + 3) * 65 + lane];
        }
        y = y >= 0.f ? y : 0.2f * y;
        outbase[(long)hd * ROW + lane] = y;
    }
}

extern "C" void kernel_launch(void* const* d_in, const int* in_sizes, int n_in,
                              void* d_out, int out_size, void* d_ws, size_t ws_size,
                              hipStream_t stream) {
    const int*   heads = (const int*)d_in[0];
    const int*   rels  = (const int*)d_in[1];
    const int*   tails = (const int*)d_in[2];
    const float* ent   = (const float*)d_in[3];
    const float* rel   = (const float*)d_in[4];
    const float* Ws    = (const float*)d_in[5];
    float* out = (float*)d_out;

    const int nE = in_sizes[0];
    const int N  = in_sizes[3] / DD;
    const int L  = in_sizes[5] / (DD * DD);
    const int NREL = in_sizes[4] / (L * DD);

    // workspace layout (ints): counts[N] | ovf[1] | offs[N+1] | permpos[E] |
    // packedF[N*CAP].  Total ~= 34N + E + 2 ints ~= 17.6 MB.
    int* counts  = (int*)d_ws;            // [N]
    int* ovf     = counts + N;            // [1]
    int* offs    = ovf + 1;               // [N+1]  (fallback only)
    int* permpos = offs + (N + 1);        // [E]    (fallback only)
    int* packedF = permpos + nE;          // [N*CAP]

    dim3 blk(256);
    int fuse_total = max(N * 16, nE);

    // ---- CSR-free build: memset + one fused kernel + guarded fallback ----
    hipMemsetAsync(counts, 0, (size_t)(N + 1) * sizeof(int), stream);  // counts+ovf
    k_build<<<(fuse_total + 255) / 256, blk, 0, stream>>>(
        ent, out, heads, rels, tails, counts, ovf, permpos, packedF, N, nE);
    k_fallback<<<1, 1024, 0, stream>>>(
        heads, rels, tails, counts, ovf, offs, permpos, packedF, N, nE);

    // ---- layers ----
    for (int l = 0; l < L; ++l) {
        k_layer<<<2048, blk, 0, stream>>>(
            offs, counts, ovf, packedF, out + l * DD, rel + (long)l * NREL * DD,
            Ws + (long)l * DD * DD, out + (l + 1) * DD, N, nE);
    }
}